// Round 1
// baseline (3155.360 us; speedup 1.0000x reference)
//
#include <hip/hip_runtime.h>

#define N_NODES 100000
#define N_EDGES 1600000
#define IN_F    128
#define HID_F   256
#define OUT_F   160
#define BN_EPS  1e-5f

// ---------------------------------------------------------------------------
// K1: edge scatter.  32 lanes per edge, float4 per lane.
//   ssum[dst] += feat[src] * w ;  deg[dst] += 1
// ---------------------------------------------------------------------------
__global__ __launch_bounds__(256) void k_scatter(
    const float* __restrict__ feat, const int* __restrict__ src,
    const int* __restrict__ dst, const float* __restrict__ ew,
    float* __restrict__ ssum, float* __restrict__ deg) {
  int tid = blockIdx.x * 256 + threadIdx.x;
  int e = tid >> 5;
  if (e >= N_EDGES) return;
  int c = tid & 31;
  int s = src[e];
  int d = dst[e];
  float w = ew[e];
  float4 f = reinterpret_cast<const float4*>(feat + (size_t)s * IN_F)[c];
  float* o = ssum + (size_t)d * IN_F + c * 4;
  atomicAdd(o + 0, f.x * w);
  atomicAdd(o + 1, f.y * w);
  atomicAdd(o + 2, f.z * w);
  atomicAdd(o + 3, f.w * w);
  if (c == 0) atomicAdd(deg + d, 1.0f);
}

// ---------------------------------------------------------------------------
// K2: y = relu( [feat | ssum/max(deg,1)] @ [W_self ; W_neigh] + bias )
//     + per-column sum / sum-of-squares accumulation (BN stats).
// Tile: 64x64, BK=16, 256 threads, 4x4 per thread.  K=256 total (2x128).
// ---------------------------------------------------------------------------
__global__ __launch_bounds__(256) void k_gemm1(
    const float* __restrict__ feat, const float* __restrict__ ssum,
    const float* __restrict__ deg, const float* __restrict__ Wself,
    const float* __restrict__ Wneigh, const float* __restrict__ bias,
    float* __restrict__ y, float* __restrict__ colsum,
    float* __restrict__ colsq) {
  __shared__ float As[16 * 68];   // transposed: As[k][r], row stride 68
  __shared__ float Bs[16 * 64];   // Bs[k][c]
  __shared__ float csum[64], csq[64];

  const int tid = threadIdx.x;
  const int tx = tid & 15, ty = tid >> 4;
  const int row0 = blockIdx.y * 64;
  const int col0 = blockIdx.x * 64;

  const int ar = tid >> 2, ac = tid & 3;    // A loader: row ar, k-chunk ac
  const int bk = tid >> 4, bc = tid & 15;   // B loader: k-row bk, col-chunk bc
  const int grow_a = row0 + ar;

  float acc[4][4] = {};

  for (int kb = 0; kb < 16; ++kb) {
    // ---- A tile (features for kb<8, ssum/deg for kb>=8) ----
    float4 av = make_float4(0.f, 0.f, 0.f, 0.f);
    if (grow_a < N_NODES) {
      if (kb < 8) {
        av = *reinterpret_cast<const float4*>(
            feat + (size_t)grow_a * IN_F + kb * 16 + ac * 4);
      } else {
        av = *reinterpret_cast<const float4*>(
            ssum + (size_t)grow_a * IN_F + (kb - 8) * 16 + ac * 4);
        float inv = 1.0f / fmaxf(deg[grow_a], 1.0f);
        av.x *= inv; av.y *= inv; av.z *= inv; av.w *= inv;
      }
    }
    As[(ac * 4 + 0) * 68 + ar] = av.x;
    As[(ac * 4 + 1) * 68 + ar] = av.y;
    As[(ac * 4 + 2) * 68 + ar] = av.z;
    As[(ac * 4 + 3) * 68 + ar] = av.w;
    // ---- B tile ----
    const float* Wb = (kb < 8) ? Wself : Wneigh;
    const int krow = (kb & 7) * 16 + bk;
    float4 bv = *reinterpret_cast<const float4*>(
        Wb + (size_t)krow * HID_F + col0 + bc * 4);
    *reinterpret_cast<float4*>(&Bs[bk * 64 + bc * 4]) = bv;
    __syncthreads();

#pragma unroll
    for (int k = 0; k < 16; ++k) {
      const float4 a4 = *reinterpret_cast<const float4*>(&As[k * 68 + ty * 4]);
      const float4 b4 = *reinterpret_cast<const float4*>(&Bs[k * 64 + tx * 4]);
      const float a[4] = {a4.x, a4.y, a4.z, a4.w};
      const float b[4] = {b4.x, b4.y, b4.z, b4.w};
#pragma unroll
      for (int i = 0; i < 4; ++i)
#pragma unroll
        for (int j = 0; j < 4; ++j)
          acc[i][j] = fmaf(a[i], b[j], acc[i][j]);
    }
    __syncthreads();
  }

  // ---- epilogue: bias + relu + store + BN partial stats ----
  if (tid < 64) { csum[tid] = 0.f; csq[tid] = 0.f; }
  __syncthreads();

  const int c0 = col0 + tx * 4;
  const float4 bb = *reinterpret_cast<const float4*>(bias + c0);
  const float bj[4] = {bb.x, bb.y, bb.z, bb.w};
  float ps[4] = {0.f, 0.f, 0.f, 0.f};
  float qs[4] = {0.f, 0.f, 0.f, 0.f};

#pragma unroll
  for (int i = 0; i < 4; ++i) {
    int gr = row0 + ty * 4 + i;
    if (gr < N_NODES) {
      float v[4];
#pragma unroll
      for (int j = 0; j < 4; ++j) {
        float t = fmaxf(acc[i][j] + bj[j], 0.f);
        v[j] = t;
        ps[j] += t;
        qs[j] += t * t;
      }
      *reinterpret_cast<float4*>(y + (size_t)gr * HID_F + c0) =
          make_float4(v[0], v[1], v[2], v[3]);
    }
  }
#pragma unroll
  for (int j = 0; j < 4; ++j) {
    atomicAdd(&csum[tx * 4 + j], ps[j]);
    atomicAdd(&csq[tx * 4 + j], qs[j]);
  }
  __syncthreads();
  if (tid < 64) {
    atomicAdd(colsum + col0 + tid, csum[tid]);
    atomicAdd(colsq + col0 + tid, csq[tid]);
  }
}

// ---------------------------------------------------------------------------
// K3: fold BN into the final FC:  W2[h][o] = fc_W[h][o]*rsig[h]*gamma[h]
//     b2[o] = fc_b[o] + sum_h (beta[h] - mu[h]*rsig[h]*gamma[h]) * fc_W[h][o]
// ---------------------------------------------------------------------------
__global__ __launch_bounds__(256) void k_finalize(
    const float* __restrict__ colsum, const float* __restrict__ colsq,
    const float* __restrict__ gamma, const float* __restrict__ beta,
    const float* __restrict__ fcW, const float* __restrict__ fcb,
    float* __restrict__ W2, float* __restrict__ b2) {
  const float invN = 1.0f / (float)N_NODES;
  if (blockIdx.x < (HID_F * OUT_F) / 256) {
    int idx = blockIdx.x * 256 + threadIdx.x;
    int h = idx / OUT_F;
    float mu = colsum[h] * invN;
    float var = colsq[h] * invN - mu * mu;
    float rs = rsqrtf(var + BN_EPS) * gamma[h];
    W2[idx] = fcW[idx] * rs;
  } else if (threadIdx.x < OUT_F) {
    int o = threadIdx.x;
    float acc = fcb[o];
    for (int h = 0; h < HID_F; ++h) {
      float mu = colsum[h] * invN;
      float var = colsq[h] * invN - mu * mu;
      float rs = rsqrtf(var + BN_EPS) * gamma[h];
      acc += (beta[h] - mu * rs) * fcW[h * OUT_F + o];
    }
    b2[o] = acc;
  }
}

// ---------------------------------------------------------------------------
// K4: out = y @ W2 + b2.   64x64 tile (col guard at 160), BK=16.
// ---------------------------------------------------------------------------
__global__ __launch_bounds__(256) void k_gemm2(
    const float* __restrict__ yin, const float* __restrict__ W2,
    const float* __restrict__ b2, float* __restrict__ out) {
  __shared__ float As[16 * 68];
  __shared__ float Bs[16 * 64];

  const int tid = threadIdx.x;
  const int tx = tid & 15, ty = tid >> 4;
  const int row0 = blockIdx.y * 64;
  const int col0 = blockIdx.x * 64;

  const int ar = tid >> 2, ac = tid & 3;
  const int bk = tid >> 4, bc = tid & 15;
  const int grow_a = row0 + ar;

  float acc[4][4] = {};

  for (int kb = 0; kb < 16; ++kb) {
    float4 av = make_float4(0.f, 0.f, 0.f, 0.f);
    if (grow_a < N_NODES)
      av = *reinterpret_cast<const float4*>(
          yin + (size_t)grow_a * HID_F + kb * 16 + ac * 4);
    As[(ac * 4 + 0) * 68 + ar] = av.x;
    As[(ac * 4 + 1) * 68 + ar] = av.y;
    As[(ac * 4 + 2) * 68 + ar] = av.z;
    As[(ac * 4 + 3) * 68 + ar] = av.w;

    const int c4 = col0 + bc * 4;
    float4 bv = make_float4(0.f, 0.f, 0.f, 0.f);
    if (c4 < OUT_F)
      bv = *reinterpret_cast<const float4*>(
          W2 + (size_t)(kb * 16 + bk) * OUT_F + c4);
    *reinterpret_cast<float4*>(&Bs[bk * 64 + bc * 4]) = bv;
    __syncthreads();

#pragma unroll
    for (int k = 0; k < 16; ++k) {
      const float4 a4 = *reinterpret_cast<const float4*>(&As[k * 68 + ty * 4]);
      const float4 b4 = *reinterpret_cast<const float4*>(&Bs[k * 64 + tx * 4]);
      const float a[4] = {a4.x, a4.y, a4.z, a4.w};
      const float b[4] = {b4.x, b4.y, b4.z, b4.w};
#pragma unroll
      for (int i = 0; i < 4; ++i)
#pragma unroll
        for (int j = 0; j < 4; ++j)
          acc[i][j] = fmaf(a[i], b[j], acc[i][j]);
    }
    __syncthreads();
  }

  const int c0 = col0 + tx * 4;
  if (c0 < OUT_F) {
    const float4 bb = *reinterpret_cast<const float4*>(b2 + c0);
#pragma unroll
    for (int i = 0; i < 4; ++i) {
      int gr = row0 + ty * 4 + i;
      if (gr < N_NODES) {
        *reinterpret_cast<float4*>(out + (size_t)gr * OUT_F + c0) =
            make_float4(acc[i][0] + bb.x, acc[i][1] + bb.y,
                        acc[i][2] + bb.z, acc[i][3] + bb.w);
      }
    }
  }
}

// ---------------------------------------------------------------------------
extern "C" void kernel_launch(void* const* d_in, const int* in_sizes, int n_in,
                              void* d_out, int out_size, void* d_ws,
                              size_t ws_size, hipStream_t stream) {
  const float* feat   = (const float*)d_in[0];
  const int*   src    = (const int*)d_in[1];
  const int*   dst    = (const int*)d_in[2];
  const float* ew     = (const float*)d_in[3];
  const float* Wself  = (const float*)d_in[4];
  const float* Wneigh = (const float*)d_in[5];
  const float* bias   = (const float*)d_in[6];
  const float* gamma  = (const float*)d_in[7];
  const float* beta   = (const float*)d_in[8];
  const float* fcW    = (const float*)d_in[9];
  const float* fcb    = (const float*)d_in[10];
  float* out = (float*)d_out;

  char* ws = (char*)d_ws;
  // layout (bytes):
  //   [0,            51,200,000)  ssum   N*128 f32
  //   [51,200,000,   51,600,000)  deg    N f32
  //   [51,600,000,   51,601,024)  colsum 256 f32
  //   [51,601,024,   51,602,048)  colsq  256 f32
  //   [51,602,048,   51,765,888)  W2     256*160 f32
  //   [51,765,888,   51,766,528)  b2     160 f32
  //   [51,766,528,  154,166,528)  y      N*256 f32
  float* ssum   = (float*)(ws + 0);
  float* deg    = (float*)(ws + 51200000);
  float* colsum = (float*)(ws + 51600000);
  float* colsq  = (float*)(ws + 51601024);
  float* W2     = (float*)(ws + 51602048);
  float* b2     = (float*)(ws + 51765888);
  float* y      = (float*)(ws + 51766528);

  // zero the accumulated buffers (ssum, deg, colsum, colsq) in one memset
  hipMemsetAsync(ws, 0, 51602048, stream);

  dim3 b256(256);
  k_scatter<<<dim3((N_EDGES * 32) / 256), b256, 0, stream>>>(
      feat, src, dst, ew, ssum, deg);
  k_gemm1<<<dim3(4, (N_NODES + 63) / 64), b256, 0, stream>>>(
      feat, ssum, deg, Wself, Wneigh, bias, y, colsum, colsq);
  k_finalize<<<dim3((HID_F * OUT_F) / 256 + 1), b256, 0, stream>>>(
      colsum, colsq, gamma, beta, fcW, fcb, W2, b2);
  k_gemm2<<<dim3((OUT_F + 63) / 64, (N_NODES + 63) / 64), b256, 0, stream>>>(
      y, W2, b2, out);
}

// Round 2
// 767.648 us; speedup vs baseline: 4.1104x; 4.1104x over previous
//
#include <hip/hip_runtime.h>

#define N_NODES 100000
#define N_EDGES 1600000
#define IN_F    128
#define HID_F   256
#define OUT_F   160
#define BN_EPS  1e-5f

// bf16 helpers (RNE), no header dependence
static __device__ inline unsigned f2bf_pair(float lo, float hi) {
  unsigned ul = __float_as_uint(lo);
  unsigned uh = __float_as_uint(hi);
  unsigned rl = (ul + 0x7fffu + ((ul >> 16) & 1u)) >> 16;
  unsigned rh = (uh + 0x7fffu + ((uh >> 16) & 1u)) >> 16;
  return rl | (rh << 16);
}

// ---------------------------------------------------------------------------
// K0: histogram of dst into cursor (pre-zeroed)
// ---------------------------------------------------------------------------
__global__ __launch_bounds__(256) void k_hist(const int* __restrict__ dst,
                                              int* __restrict__ cursor) {
  int e = blockIdx.x * 256 + threadIdx.x;
  if (e < N_EDGES) atomicAdd(&cursor[dst[e]], 1);
}

// ---------------------------------------------------------------------------
// K1: single-block exclusive scan: cursor(counts) -> cursor & offs (excl),
//     offs[N] = E.  1024 threads, shfl wave-scan + 16-wave LDS combine.
// ---------------------------------------------------------------------------
__global__ __launch_bounds__(1024) void k_scan(int* __restrict__ cursor,
                                               int* __restrict__ offs) {
  __shared__ int wsum[16];
  __shared__ int chunk_total;
  __shared__ int carry;
  const int tid = threadIdx.x;
  const int lane = tid & 63, wid = tid >> 6;
  if (tid == 0) carry = 0;
  __syncthreads();
  for (int base = 0; base < N_NODES; base += 1024) {
    int i = base + tid;
    int v = (i < N_NODES) ? cursor[i] : 0;
    int x = v;
#pragma unroll
    for (int off = 1; off < 64; off <<= 1) {
      int t = __shfl_up(x, off, 64);
      if (lane >= off) x += t;
    }
    if (lane == 63) wsum[wid] = x;
    __syncthreads();
    if (wid == 0) {
      int s = (lane < 16) ? wsum[lane] : 0;
      int y = s;
#pragma unroll
      for (int off = 1; off < 16; off <<= 1) {
        int t = __shfl_up(y, off, 64);
        if (lane >= off) y += t;
      }
      if (lane < 16) wsum[lane] = y - s;  // exclusive wave offset in chunk
      if (lane == 15) chunk_total = y;
    }
    __syncthreads();
    int excl = carry + wsum[wid] + (x - v);
    if (i < N_NODES) { offs[i] = excl; cursor[i] = excl; }
    __syncthreads();  // all reads of carry done before update
    if (tid == 0) carry += chunk_total;
    __syncthreads();
  }
  if (tid == 0) offs[N_NODES] = carry;
}

// ---------------------------------------------------------------------------
// K2: place (src, w) pairs into CSR slots
// ---------------------------------------------------------------------------
__global__ __launch_bounds__(256) void k_place(
    const int* __restrict__ src, const int* __restrict__ dst,
    const float* __restrict__ ew, int* __restrict__ cursor,
    int2* __restrict__ pairs) {
  int e = blockIdx.x * 256 + threadIdx.x;
  if (e < N_EDGES) {
    int p = atomicAdd(&cursor[dst[e]], 1);
    pairs[p] = make_int2(src[e], __float_as_int(ew[e]));
  }
}

// ---------------------------------------------------------------------------
// K3: pull-gather. One wave per node; lane handles 2 of 128 feats.
//     neigh[node] = (sum_e w*feat[src]) / max(deg,1), stored bf16.
// ---------------------------------------------------------------------------
__global__ __launch_bounds__(256) void k_gather(
    const float* __restrict__ feat, const int* __restrict__ offs,
    const int2* __restrict__ pairs, unsigned* __restrict__ neigh) {
  int node = blockIdx.x * 4 + (threadIdx.x >> 6);
  if (node >= N_NODES) return;
  int lane = threadIdx.x & 63;
  int start = offs[node], end = offs[node + 1];
  int deg = end - start;
  float2 acc = make_float2(0.f, 0.f);
  for (int k0 = start; k0 < end; k0 += 64) {
    int2 pr = make_int2(0, 0);
    if (k0 + lane < end) pr = pairs[k0 + lane];
    int cnt = min(64, end - k0);
    for (int k = 0; k < cnt; ++k) {
      int s = __shfl(pr.x, k, 64);
      float w = __int_as_float(__shfl(pr.y, k, 64));
      const float2 f = *reinterpret_cast<const float2*>(
          feat + (size_t)s * IN_F + lane * 2);
      acc.x = fmaf(w, f.x, acc.x);
      acc.y = fmaf(w, f.y, acc.y);
    }
  }
  float inv = (deg > 0) ? (1.0f / (float)deg) : 0.f;
  neigh[(size_t)node * 64 + lane] = f2bf_pair(acc.x * inv, acc.y * inv);
}

// ---------------------------------------------------------------------------
// K4: y = relu( [feat | neigh] @ [W_self ; W_neigh] + bias ) + BN col stats.
// Tile 64x64, BK=16, 256 threads, 4x4/thread. neigh is bf16 (pre-normalized).
// ---------------------------------------------------------------------------
__global__ __launch_bounds__(256) void k_gemm1(
    const float* __restrict__ feat, const unsigned* __restrict__ neigh,
    const float* __restrict__ Wself, const float* __restrict__ Wneigh,
    const float* __restrict__ bias, float* __restrict__ y,
    float* __restrict__ colsum, float* __restrict__ colsq) {
  __shared__ float As[16 * 68];
  __shared__ float Bs[16 * 64];
  __shared__ float csum[64], csq[64];

  const int tid = threadIdx.x;
  const int tx = tid & 15, ty = tid >> 4;
  const int row0 = blockIdx.y * 64;
  const int col0 = blockIdx.x * 64;

  const int ar = tid >> 2, ac = tid & 3;
  const int bk = tid >> 4, bc = tid & 15;
  const int grow_a = row0 + ar;

  float acc[4][4] = {};

  for (int kb = 0; kb < 16; ++kb) {
    float4 av = make_float4(0.f, 0.f, 0.f, 0.f);
    if (grow_a < N_NODES) {
      if (kb < 8) {
        av = *reinterpret_cast<const float4*>(
            feat + (size_t)grow_a * IN_F + kb * 16 + ac * 4);
      } else {
        uint2 u = *reinterpret_cast<const uint2*>(
            neigh + (size_t)grow_a * 64 + (kb - 8) * 8 + ac * 2);
        av.x = __uint_as_float(u.x << 16);
        av.y = __uint_as_float(u.x & 0xffff0000u);
        av.z = __uint_as_float(u.y << 16);
        av.w = __uint_as_float(u.y & 0xffff0000u);
      }
    }
    As[(ac * 4 + 0) * 68 + ar] = av.x;
    As[(ac * 4 + 1) * 68 + ar] = av.y;
    As[(ac * 4 + 2) * 68 + ar] = av.z;
    As[(ac * 4 + 3) * 68 + ar] = av.w;

    const float* Wb = (kb < 8) ? Wself : Wneigh;
    const int krow = (kb & 7) * 16 + bk;
    float4 bv = *reinterpret_cast<const float4*>(
        Wb + (size_t)krow * HID_F + col0 + bc * 4);
    *reinterpret_cast<float4*>(&Bs[bk * 64 + bc * 4]) = bv;
    __syncthreads();

#pragma unroll
    for (int k = 0; k < 16; ++k) {
      const float4 a4 = *reinterpret_cast<const float4*>(&As[k * 68 + ty * 4]);
      const float4 b4 = *reinterpret_cast<const float4*>(&Bs[k * 64 + tx * 4]);
      const float a[4] = {a4.x, a4.y, a4.z, a4.w};
      const float b[4] = {b4.x, b4.y, b4.z, b4.w};
#pragma unroll
      for (int i = 0; i < 4; ++i)
#pragma unroll
        for (int j = 0; j < 4; ++j)
          acc[i][j] = fmaf(a[i], b[j], acc[i][j]);
    }
    __syncthreads();
  }

  if (tid < 64) { csum[tid] = 0.f; csq[tid] = 0.f; }
  __syncthreads();

  const int c0 = col0 + tx * 4;
  const float4 bb = *reinterpret_cast<const float4*>(bias + c0);
  const float bj[4] = {bb.x, bb.y, bb.z, bb.w};
  float ps[4] = {0.f, 0.f, 0.f, 0.f};
  float qs[4] = {0.f, 0.f, 0.f, 0.f};

#pragma unroll
  for (int i = 0; i < 4; ++i) {
    int gr = row0 + ty * 4 + i;
    if (gr < N_NODES) {
      float v[4];
#pragma unroll
      for (int j = 0; j < 4; ++j) {
        float t = fmaxf(acc[i][j] + bj[j], 0.f);
        v[j] = t;
        ps[j] += t;
        qs[j] += t * t;
      }
      *reinterpret_cast<float4*>(y + (size_t)gr * HID_F + c0) =
          make_float4(v[0], v[1], v[2], v[3]);
    }
  }
#pragma unroll
  for (int j = 0; j < 4; ++j) {
    atomicAdd(&csum[tx * 4 + j], ps[j]);
    atomicAdd(&csq[tx * 4 + j], qs[j]);
  }
  __syncthreads();
  if (tid < 64) {
    atomicAdd(colsum + col0 + tid, csum[tid]);
    atomicAdd(colsq + col0 + tid, csq[tid]);
  }
}

// ---------------------------------------------------------------------------
// K5: fold BN into final FC weights
// ---------------------------------------------------------------------------
__global__ __launch_bounds__(256) void k_finalize(
    const float* __restrict__ colsum, const float* __restrict__ colsq,
    const float* __restrict__ gamma, const float* __restrict__ beta,
    const float* __restrict__ fcW, const float* __restrict__ fcb,
    float* __restrict__ W2, float* __restrict__ b2) {
  const float invN = 1.0f / (float)N_NODES;
  if (blockIdx.x < (HID_F * OUT_F) / 256) {
    int idx = blockIdx.x * 256 + threadIdx.x;
    int h = idx / OUT_F;
    float mu = colsum[h] * invN;
    float var = colsq[h] * invN - mu * mu;
    float rs = rsqrtf(var + BN_EPS) * gamma[h];
    W2[idx] = fcW[idx] * rs;
  } else if (threadIdx.x < OUT_F) {
    int o = threadIdx.x;
    float acc = fcb[o];
    for (int h = 0; h < HID_F; ++h) {
      float mu = colsum[h] * invN;
      float var = colsq[h] * invN - mu * mu;
      float rs = rsqrtf(var + BN_EPS) * gamma[h];
      acc += (beta[h] - mu * rs) * fcW[h * OUT_F + o];
    }
    b2[o] = acc;
  }
}

// ---------------------------------------------------------------------------
// K6: out = y @ W2 + b2
// ---------------------------------------------------------------------------
__global__ __launch_bounds__(256) void k_gemm2(
    const float* __restrict__ yin, const float* __restrict__ W2,
    const float* __restrict__ b2, float* __restrict__ out) {
  __shared__ float As[16 * 68];
  __shared__ float Bs[16 * 64];

  const int tid = threadIdx.x;
  const int tx = tid & 15, ty = tid >> 4;
  const int row0 = blockIdx.y * 64;
  const int col0 = blockIdx.x * 64;

  const int ar = tid >> 2, ac = tid & 3;
  const int bk = tid >> 4, bc = tid & 15;
  const int grow_a = row0 + ar;

  float acc[4][4] = {};

  for (int kb = 0; kb < 16; ++kb) {
    float4 av = make_float4(0.f, 0.f, 0.f, 0.f);
    if (grow_a < N_NODES)
      av = *reinterpret_cast<const float4*>(
          yin + (size_t)grow_a * HID_F + kb * 16 + ac * 4);
    As[(ac * 4 + 0) * 68 + ar] = av.x;
    As[(ac * 4 + 1) * 68 + ar] = av.y;
    As[(ac * 4 + 2) * 68 + ar] = av.z;
    As[(ac * 4 + 3) * 68 + ar] = av.w;

    const int c4 = col0 + bc * 4;
    float4 bv = make_float4(0.f, 0.f, 0.f, 0.f);
    if (c4 < OUT_F)
      bv = *reinterpret_cast<const float4*>(
          W2 + (size_t)(kb * 16 + bk) * OUT_F + c4);
    *reinterpret_cast<float4*>(&Bs[bk * 64 + bc * 4]) = bv;
    __syncthreads();

#pragma unroll
    for (int k = 0; k < 16; ++k) {
      const float4 a4 = *reinterpret_cast<const float4*>(&As[k * 68 + ty * 4]);
      const float4 b4 = *reinterpret_cast<const float4*>(&Bs[k * 64 + tx * 4]);
      const float a[4] = {a4.x, a4.y, a4.z, a4.w};
      const float b[4] = {b4.x, b4.y, b4.z, b4.w};
#pragma unroll
      for (int i = 0; i < 4; ++i)
#pragma unroll
        for (int j = 0; j < 4; ++j)
          acc[i][j] = fmaf(a[i], b[j], acc[i][j]);
    }
    __syncthreads();
  }

  const int c0 = col0 + tx * 4;
  if (c0 < OUT_F) {
    const float4 bb = *reinterpret_cast<const float4*>(b2 + c0);
#pragma unroll
    for (int i = 0; i < 4; ++i) {
      int gr = row0 + ty * 4 + i;
      if (gr < N_NODES) {
        *reinterpret_cast<float4*>(out + (size_t)gr * OUT_F + c0) =
            make_float4(acc[i][0] + bb.x, acc[i][1] + bb.y,
                        acc[i][2] + bb.z, acc[i][3] + bb.w);
      }
    }
  }
}

// ---------------------------------------------------------------------------
extern "C" void kernel_launch(void* const* d_in, const int* in_sizes, int n_in,
                              void* d_out, int out_size, void* d_ws,
                              size_t ws_size, hipStream_t stream) {
  const float* feat   = (const float*)d_in[0];
  const int*   src    = (const int*)d_in[1];
  const int*   dst    = (const int*)d_in[2];
  const float* ew     = (const float*)d_in[3];
  const float* Wself  = (const float*)d_in[4];
  const float* Wneigh = (const float*)d_in[5];
  const float* bias   = (const float*)d_in[6];
  const float* gamma  = (const float*)d_in[7];
  const float* beta   = (const float*)d_in[8];
  const float* fcW    = (const float*)d_in[9];
  const float* fcb    = (const float*)d_in[10];
  float* out = (float*)d_out;

  char* ws = (char*)d_ws;
  // layout (bytes):
  //   [0,           400,000)   cursor  N i32          (zeroed)
  //   [400,000,     401,024)   colsum  256 f32        (zeroed)
  //   [401,024,     402,048)   colsq   256 f32        (zeroed)
  //   [402,048,     802,064)   offs    (N+1) i32
  //   [802,176,  13,602,176)   pairs   E int2
  //   [13,602,176, 39,202,176) neigh   N*128 bf16 (as N*64 u32)
  //   [39,202,176, 39,366,016) W2      256*160 f32
  //   [39,366,016, 39,366,656) b2      160 f32
  //   [39,366,656,141,766,656) y       N*256 f32
  int*      cursor = (int*)(ws + 0);
  float*    colsum = (float*)(ws + 400000);
  float*    colsq  = (float*)(ws + 401024);
  int*      offs   = (int*)(ws + 402048);
  int2*     pairs  = (int2*)(ws + 802176);
  unsigned* neigh  = (unsigned*)(ws + 13602176);
  float*    W2     = (float*)(ws + 39202176);
  float*    b2     = (float*)(ws + 39366016);
  float*    y      = (float*)(ws + 39366656);

  hipMemsetAsync(ws, 0, 402048, stream);

  dim3 b256(256);
  k_hist<<<dim3((N_EDGES + 255) / 256), b256, 0, stream>>>(dst, cursor);
  k_scan<<<dim3(1), dim3(1024), 0, stream>>>(cursor, offs);
  k_place<<<dim3((N_EDGES + 255) / 256), b256, 0, stream>>>(
      src, dst, ew, cursor, pairs);
  k_gather<<<dim3((N_NODES + 3) / 4), b256, 0, stream>>>(
      feat, offs, pairs, neigh);
  k_gemm1<<<dim3(4, (N_NODES + 63) / 64), b256, 0, stream>>>(
      feat, neigh, Wself, Wneigh, bias, y, colsum, colsq);
  k_finalize<<<dim3((HID_F * OUT_F) / 256 + 1), b256, 0, stream>>>(
      colsum, colsq, gamma, beta, fcW, fcb, W2, b2);
  k_gemm2<<<dim3((OUT_F + 63) / 64, (N_NODES + 63) / 64), b256, 0, stream>>>(
      y, W2, b2, out);
}

// Round 3
// 562.383 us; speedup vs baseline: 5.6107x; 1.3650x over previous
//
#include <hip/hip_runtime.h>

#define N_NODES 100000
#define N_EDGES 1600000
#define IN_F    128
#define HID_F   256
#define OUT_F   160
#define BN_EPS  1e-5f

typedef __attribute__((ext_vector_type(8))) short bf16x8;
typedef __attribute__((ext_vector_type(4))) float f32x4;

static __device__ inline unsigned short f2bf(float x) {
  unsigned u = __float_as_uint(x);
  return (unsigned short)((u + 0x7fffu + ((u >> 16) & 1u)) >> 16);
}
static __device__ inline unsigned f2bf_pair(float lo, float hi) {
  return (unsigned)f2bf(lo) | ((unsigned)f2bf(hi) << 16);
}

// ---------------------------------------------------------------------------
// K0: histogram of dst into cursor (pre-zeroed)
// ---------------------------------------------------------------------------
__global__ __launch_bounds__(256) void k_hist(const int* __restrict__ dst,
                                              int* __restrict__ cursor) {
  int e = blockIdx.x * 256 + threadIdx.x;
  if (e < N_EDGES) atomicAdd(&cursor[dst[e]], 1);
}

// ---------------------------------------------------------------------------
// K1: single-block exclusive scan (validated round 2)
// ---------------------------------------------------------------------------
__global__ __launch_bounds__(1024) void k_scan(int* __restrict__ cursor,
                                               int* __restrict__ offs) {
  __shared__ int wsum[16];
  __shared__ int chunk_total;
  __shared__ int carry;
  const int tid = threadIdx.x;
  const int lane = tid & 63, wid = tid >> 6;
  if (tid == 0) carry = 0;
  __syncthreads();
  for (int base = 0; base < N_NODES; base += 1024) {
    int i = base + tid;
    int v = (i < N_NODES) ? cursor[i] : 0;
    int x = v;
#pragma unroll
    for (int off = 1; off < 64; off <<= 1) {
      int t = __shfl_up(x, off, 64);
      if (lane >= off) x += t;
    }
    if (lane == 63) wsum[wid] = x;
    __syncthreads();
    if (wid == 0) {
      int s = (lane < 16) ? wsum[lane] : 0;
      int y = s;
#pragma unroll
      for (int off = 1; off < 16; off <<= 1) {
        int t = __shfl_up(y, off, 64);
        if (lane >= off) y += t;
      }
      if (lane < 16) wsum[lane] = y - s;
      if (lane == 15) chunk_total = y;
    }
    __syncthreads();
    int excl = carry + wsum[wid] + (x - v);
    if (i < N_NODES) { offs[i] = excl; cursor[i] = excl; }
    __syncthreads();
    if (tid == 0) carry += chunk_total;
    __syncthreads();
  }
  if (tid == 0) offs[N_NODES] = carry;
}

// ---------------------------------------------------------------------------
// K2: place (src, w) pairs into CSR slots
// ---------------------------------------------------------------------------
__global__ __launch_bounds__(256) void k_place(
    const int* __restrict__ src, const int* __restrict__ dst,
    const float* __restrict__ ew, int* __restrict__ cursor,
    int2* __restrict__ pairs) {
  int e = blockIdx.x * 256 + threadIdx.x;
  if (e < N_EDGES) {
    int p = atomicAdd(&cursor[dst[e]], 1);
    pairs[p] = make_int2(src[e], __float_as_int(ew[e]));
  }
}

// ---------------------------------------------------------------------------
// K3: feat fp32 -> bf16 into A1 columns 0..127 (row stride 256 bf16)
// ---------------------------------------------------------------------------
__global__ __launch_bounds__(256) void k_convert(
    const float* __restrict__ feat, unsigned* __restrict__ A1u) {
  long long idx = (long long)blockIdx.x * 256 + threadIdx.x;  // 1.6M threads
  long long fidx = idx * 8;
  if (fidx >= (long long)N_NODES * IN_F) return;
  int node = (int)(fidx >> 7);
  int c0 = (int)(fidx & 127);
  float4 f0 = *reinterpret_cast<const float4*>(feat + fidx);
  float4 f1 = *reinterpret_cast<const float4*>(feat + fidx + 4);
  uint4 o;
  o.x = f2bf_pair(f0.x, f0.y);
  o.y = f2bf_pair(f0.z, f0.w);
  o.z = f2bf_pair(f1.x, f1.y);
  o.w = f2bf_pair(f1.z, f1.w);
  *reinterpret_cast<uint4*>(A1u + (size_t)node * 128 + (c0 >> 1)) = o;
}

// ---------------------------------------------------------------------------
// K4: build W1T[c][k] = bf16( k<128 ? Wself[k][c] : Wneigh[k-128][c] )
// ---------------------------------------------------------------------------
__global__ __launch_bounds__(256) void k_prepw(
    const float* __restrict__ Wself, const float* __restrict__ Wneigh,
    unsigned short* __restrict__ W1T) {
  int c = blockIdx.x;     // 0..255
  int k = threadIdx.x;    // 0..255
  float v = (k < 128) ? Wself[(size_t)k * HID_F + c]
                      : Wneigh[(size_t)(k - 128) * HID_F + c];
  W1T[(size_t)c * 256 + k] = f2bf(v);
}

// ---------------------------------------------------------------------------
// K5: pull-gather -> A1 columns 128..255 (bf16, pre-normalized by deg)
// ---------------------------------------------------------------------------
__global__ __launch_bounds__(256) void k_gather(
    const float* __restrict__ feat, const int* __restrict__ offs,
    const int2* __restrict__ pairs, unsigned* __restrict__ A1u) {
  int node = blockIdx.x * 4 + (threadIdx.x >> 6);
  if (node >= N_NODES) return;
  int lane = threadIdx.x & 63;
  int start = offs[node], end = offs[node + 1];
  int deg = end - start;
  float2 acc = make_float2(0.f, 0.f);
  for (int k0 = start; k0 < end; k0 += 64) {
    int2 pr = make_int2(0, 0);
    if (k0 + lane < end) pr = pairs[k0 + lane];
    int cnt = min(64, end - k0);
    for (int k = 0; k < cnt; ++k) {
      int s = __shfl(pr.x, k, 64);
      float w = __int_as_float(__shfl(pr.y, k, 64));
      const float2 f = *reinterpret_cast<const float2*>(
          feat + (size_t)s * IN_F + lane * 2);
      acc.x = fmaf(w, f.x, acc.x);
      acc.y = fmaf(w, f.y, acc.y);
    }
  }
  float inv = (deg > 0) ? (1.0f / (float)deg) : 0.f;
  A1u[(size_t)node * 128 + 64 + lane] = f2bf_pair(acc.x * inv, acc.y * inv);
}

// ---------------------------------------------------------------------------
// K6: GEMM1 (MFMA bf16): y = relu(A1 @ W1 + bias), y stored bf16.
//     + fused BN column stats (colsum/colsq).
// Tile 128x256, BK=64, 512 threads = 8 waves (2 x 4), wave tile 64x64.
// ---------------------------------------------------------------------------
__global__ __launch_bounds__(512) void k_gemm1(
    const unsigned short* __restrict__ A1, const unsigned short* __restrict__ W1T,
    const float* __restrict__ bias, unsigned short* __restrict__ y,
    float* __restrict__ colsum, float* __restrict__ colsq) {
  __shared__ short As[128 * 72];   // [row][k] pad 64->72
  __shared__ short Bs[256 * 72];   // [col][k] pad
  __shared__ float csum[256], csq[256];

  const int tid = threadIdx.x;
  const int lane = tid & 63;
  const int wid = tid >> 6;
  const int wr = wid >> 2, wc = wid & 3;
  const int l16 = lane & 15, lk = lane >> 4;
  const int row0 = blockIdx.x * 128;

  const int sr = tid >> 3;        // 0..63 staging row
  const int sc = (tid & 7) * 8;   // k-chunk within BK

  f32x4 acc[4][4];
#pragma unroll
  for (int m = 0; m < 4; ++m)
#pragma unroll
    for (int n = 0; n < 4; ++n) acc[m][n] = (f32x4){0.f, 0.f, 0.f, 0.f};

  for (int ks = 0; ks < 4; ++ks) {
    const int k0 = ks * 64;
    // stage A: 128 rows x 64 k (2 passes of 64 rows)
#pragma unroll
    for (int p = 0; p < 2; ++p) {
      int r = p * 64 + sr;
      int gr = row0 + r;
      bf16x8 v = {};
      if (gr < N_NODES)
        v = *reinterpret_cast<const bf16x8*>(A1 + (size_t)gr * 256 + k0 + sc);
      *reinterpret_cast<bf16x8*>(&As[r * 72 + sc]) = v;
    }
    // stage B: 256 cols x 64 k (4 passes)
#pragma unroll
    for (int p = 0; p < 4; ++p) {
      int c = p * 64 + sr;
      bf16x8 v = *reinterpret_cast<const bf16x8*>(
          W1T + (size_t)c * 256 + k0 + sc);
      *reinterpret_cast<bf16x8*>(&Bs[c * 72 + sc]) = v;
    }
    __syncthreads();

#pragma unroll
    for (int kk = 0; kk < 2; ++kk) {
      bf16x8 af[4], bfr[4];
#pragma unroll
      for (int m = 0; m < 4; ++m)
        af[m] = *reinterpret_cast<const bf16x8*>(
            &As[(wr * 64 + m * 16 + l16) * 72 + kk * 32 + lk * 8]);
#pragma unroll
      for (int n = 0; n < 4; ++n)
        bfr[n] = *reinterpret_cast<const bf16x8*>(
            &Bs[(wc * 64 + n * 16 + l16) * 72 + kk * 32 + lk * 8]);
#pragma unroll
      for (int m = 0; m < 4; ++m)
#pragma unroll
        for (int n = 0; n < 4; ++n)
          acc[m][n] = __builtin_amdgcn_mfma_f32_16x16x32_bf16(
              af[m], bfr[n], acc[m][n], 0, 0, 0);
    }
    __syncthreads();
  }

  // epilogue: bias + relu + bf16 store + BN col stats
  for (int i = tid; i < 256; i += 512) { csum[i] = 0.f; csq[i] = 0.f; }
  __syncthreads();

  float ps[4] = {0.f, 0.f, 0.f, 0.f};
  float qs[4] = {0.f, 0.f, 0.f, 0.f};
#pragma unroll
  for (int n = 0; n < 4; ++n) {
    const int c = wc * 64 + n * 16 + l16;
    const float bb = bias[c];
#pragma unroll
    for (int m = 0; m < 4; ++m) {
      const int rbase = row0 + wr * 64 + m * 16 + lk * 4;
#pragma unroll
      for (int r = 0; r < 4; ++r) {
        int gr = rbase + r;
        if (gr < N_NODES) {
          float t = fmaxf(acc[m][n][r] + bb, 0.f);
          ps[n] += t;
          qs[n] += t * t;
          y[(size_t)gr * 256 + c] = f2bf(t);
        }
      }
    }
  }
#pragma unroll
  for (int n = 0; n < 4; ++n) {
    ps[n] += __shfl_xor(ps[n], 16, 64);
    ps[n] += __shfl_xor(ps[n], 32, 64);
    qs[n] += __shfl_xor(qs[n], 16, 64);
    qs[n] += __shfl_xor(qs[n], 32, 64);
    if (lk == 0) {
      atomicAdd(&csum[wc * 64 + n * 16 + l16], ps[n]);
      atomicAdd(&csq[wc * 64 + n * 16 + l16], qs[n]);
    }
  }
  __syncthreads();
  for (int i = tid; i < 256; i += 512) {
    atomicAdd(&colsum[i], csum[i]);
    atomicAdd(&colsq[i], csq[i]);
  }
}

// ---------------------------------------------------------------------------
// K7: BN fold -> W2T[o][h] bf16 (o padded to 192), b2[o] f32
// ---------------------------------------------------------------------------
__global__ __launch_bounds__(256) void k_finalize(
    const float* __restrict__ colsum, const float* __restrict__ colsq,
    const float* __restrict__ gamma, const float* __restrict__ beta,
    const float* __restrict__ fcW, const float* __restrict__ fcb,
    unsigned short* __restrict__ W2T, float* __restrict__ b2) {
  const float invN = 1.0f / (float)N_NODES;
  if (blockIdx.x < 192) {
    int o = blockIdx.x, h = threadIdx.x;
    unsigned short v = 0;
    if (o < OUT_F) {
      float mu = colsum[h] * invN;
      float var = colsq[h] * invN - mu * mu;
      float rs = rsqrtf(var + BN_EPS) * gamma[h];
      v = f2bf(fcW[(size_t)h * OUT_F + o] * rs);
    }
    W2T[(size_t)o * 256 + h] = v;
  } else if (threadIdx.x < OUT_F) {
    int o = threadIdx.x;
    float acc = fcb[o];
    for (int h = 0; h < HID_F; ++h) {
      float mu = colsum[h] * invN;
      float var = colsq[h] * invN - mu * mu;
      float rs = rsqrtf(var + BN_EPS) * gamma[h];
      acc += (beta[h] - mu * rs) * fcW[(size_t)h * OUT_F + o];
    }
    b2[o] = acc;
  }
}

// ---------------------------------------------------------------------------
// K8: GEMM2 (MFMA bf16): out = y @ W2 + b2.
// Tile 128x192, BK=64, 512 threads = 8 waves (2 x 4), wave tile 64x48.
// ---------------------------------------------------------------------------
__global__ __launch_bounds__(512) void k_gemm2(
    const unsigned short* __restrict__ y, const unsigned short* __restrict__ W2T,
    const float* __restrict__ b2, float* __restrict__ out) {
  __shared__ short As[128 * 72];
  __shared__ short Bs[192 * 72];

  const int tid = threadIdx.x;
  const int lane = tid & 63;
  const int wid = tid >> 6;
  const int wr = wid >> 2, wc = wid & 3;
  const int l16 = lane & 15, lk = lane >> 4;
  const int row0 = blockIdx.x * 128;

  const int sr = tid >> 3;
  const int sc = (tid & 7) * 8;

  f32x4 acc[4][3];
#pragma unroll
  for (int m = 0; m < 4; ++m)
#pragma unroll
    for (int n = 0; n < 3; ++n) acc[m][n] = (f32x4){0.f, 0.f, 0.f, 0.f};

  for (int ks = 0; ks < 4; ++ks) {
    const int k0 = ks * 64;
#pragma unroll
    for (int p = 0; p < 2; ++p) {
      int r = p * 64 + sr;
      int gr = row0 + r;
      bf16x8 v = {};
      if (gr < N_NODES)
        v = *reinterpret_cast<const bf16x8*>(y + (size_t)gr * 256 + k0 + sc);
      *reinterpret_cast<bf16x8*>(&As[r * 72 + sc]) = v;
    }
#pragma unroll
    for (int p = 0; p < 3; ++p) {
      int c = p * 64 + sr;
      bf16x8 v = *reinterpret_cast<const bf16x8*>(
          W2T + (size_t)c * 256 + k0 + sc);
      *reinterpret_cast<bf16x8*>(&Bs[c * 72 + sc]) = v;
    }
    __syncthreads();

#pragma unroll
    for (int kk = 0; kk < 2; ++kk) {
      bf16x8 af[4], bfr[3];
#pragma unroll
      for (int m = 0; m < 4; ++m)
        af[m] = *reinterpret_cast<const bf16x8*>(
            &As[(wr * 64 + m * 16 + l16) * 72 + kk * 32 + lk * 8]);
#pragma unroll
      for (int n = 0; n < 3; ++n)
        bfr[n] = *reinterpret_cast<const bf16x8*>(
            &Bs[(wc * 48 + n * 16 + l16) * 72 + kk * 32 + lk * 8]);
#pragma unroll
      for (int m = 0; m < 4; ++m)
#pragma unroll
        for (int n = 0; n < 3; ++n)
          acc[m][n] = __builtin_amdgcn_mfma_f32_16x16x32_bf16(
              af[m], bfr[n], acc[m][n], 0, 0, 0);
    }
    __syncthreads();
  }

#pragma unroll
  for (int n = 0; n < 3; ++n) {
    const int c = wc * 48 + n * 16 + l16;
    if (c < OUT_F) {
      const float bb = b2[c];
#pragma unroll
      for (int m = 0; m < 4; ++m) {
        const int rbase = row0 + wr * 64 + m * 16 + lk * 4;
#pragma unroll
        for (int r = 0; r < 4; ++r) {
          int gr = rbase + r;
          if (gr < N_NODES)
            out[(size_t)gr * OUT_F + c] = acc[m][n][r] + bb;
        }
      }
    }
  }
}

// ---------------------------------------------------------------------------
extern "C" void kernel_launch(void* const* d_in, const int* in_sizes, int n_in,
                              void* d_out, int out_size, void* d_ws,
                              size_t ws_size, hipStream_t stream) {
  const float* feat   = (const float*)d_in[0];
  const int*   src    = (const int*)d_in[1];
  const int*   dst    = (const int*)d_in[2];
  const float* ew     = (const float*)d_in[3];
  const float* Wself  = (const float*)d_in[4];
  const float* Wneigh = (const float*)d_in[5];
  const float* bias   = (const float*)d_in[6];
  const float* gamma  = (const float*)d_in[7];
  const float* beta   = (const float*)d_in[8];
  const float* fcW    = (const float*)d_in[9];
  const float* fcb    = (const float*)d_in[10];
  float* out = (float*)d_out;

  char* ws = (char*)d_ws;
  // layout (bytes):
  //   [0,           400,000)   cursor  N i32           (zeroed)
  //   [400,000,     401,024)   colsum  256 f32         (zeroed)
  //   [401,024,     402,048)   colsq   256 f32         (zeroed)
  //   [402,048,     802,064)   offs    (N+1) i32
  //   [802,176,  13,602,176)   pairs   E int2
  //   [13,602,176, 64,802,176) A1      N*256 bf16  (feat | neigh)
  //   [64,802,176, 64,933,248) W1T     256*256 bf16
  //   [64,933,248, 65,031,552) W2T     192*256 bf16
  //   [65,031,552, 65,032,192) b2      160 f32
  //   [65,032,192,116,232,192) y       N*256 bf16
  int*            cursor = (int*)(ws + 0);
  float*          colsum = (float*)(ws + 400000);
  float*          colsq  = (float*)(ws + 401024);
  int*            offs   = (int*)(ws + 402048);
  int2*           pairs  = (int2*)(ws + 802176);
  unsigned*       A1u    = (unsigned*)(ws + 13602176);
  unsigned short* A1     = (unsigned short*)(ws + 13602176);
  unsigned short* W1T    = (unsigned short*)(ws + 64802176);
  unsigned short* W2T    = (unsigned short*)(ws + 64933248);
  float*          b2     = (float*)(ws + 65031552);
  unsigned short* y      = (unsigned short*)(ws + 65032192);

  hipMemsetAsync(ws, 0, 402048, stream);

  dim3 b256(256);
  k_hist<<<dim3((N_EDGES + 255) / 256), b256, 0, stream>>>(dst, cursor);
  k_scan<<<dim3(1), dim3(1024), 0, stream>>>(cursor, offs);
  k_place<<<dim3((N_EDGES + 255) / 256), b256, 0, stream>>>(
      src, dst, ew, cursor, pairs);
  k_convert<<<dim3((N_NODES * IN_F / 8 + 255) / 256), b256, 0, stream>>>(
      feat, A1u);
  k_prepw<<<dim3(256), b256, 0, stream>>>(Wself, Wneigh, W1T);
  k_gather<<<dim3((N_NODES + 3) / 4), b256, 0, stream>>>(
      feat, offs, pairs, A1u);
  k_gemm1<<<dim3((N_NODES + 127) / 128), dim3(512), 0, stream>>>(
      A1, W1T, bias, y, colsum, colsq);
  k_finalize<<<dim3(193), b256, 0, stream>>>(
      colsum, colsq, gamma, beta, fcW, fcb, W2T, b2);
  k_gemm2<<<dim3((N_NODES + 127) / 128), dim3(512), 0, stream>>>(
      y, W2T, b2, out);
}